// Round 12
// baseline (488.915 us; speedup 1.0000x reference)
//
#include <hip/hip_runtime.h>

typedef unsigned int u32;
typedef __bf16 bf16x8 __attribute__((ext_vector_type(8)));
typedef __bf16 bf16x4v __attribute__((ext_vector_type(4)));
typedef _Float16 f16x8 __attribute__((ext_vector_type(8)));
typedef float f32x4 __attribute__((ext_vector_type(4)));

#define Tn 4
#define Bn 32
#define Cn 384
#define Nn 196
#define Hn 12
#define CNn (Cn*Nn)         // 75264
#define BCNn (Bn*CNn)       // 2408448
#define BHNn (Bn*Hn*Nn)     // 75264
#define PBITS (Tn*BHNn)     // 301056
#define TBCNn (Tn*BCNn)     // 9633792
#define NCOLS 6272          // B*N
#define WSZ 147456          // 384*384

// fp32 -> 3-way bf16 split (residual ~2^-24 rel)
__device__ __forceinline__ void split3(float v, __bf16& h, __bf16& m, __bf16& l) {
  h = (__bf16)v;  float r = v - (float)h;
  m = (__bf16)r;  float r2 = r - (float)m;
  l = (__bf16)r2;
}
// fp32 -> 2-way f16 split (residual ~2^-22 rel)
__device__ __forceinline__ void split2h(float v, _Float16& h, _Float16& l) {
  h = (_Float16)v;  l = (_Float16)(v - (float)h);
}

// direct global->LDS 16B copy: lane i lands at ldsbase + i*16 (wave-uniform base)
__device__ __forceinline__ void gl_lds16(const void* g, void* l) {
  __builtin_amdgcn_global_load_lds(
      (const __attribute__((address_space(1))) unsigned int*)g,
      (__attribute__((address_space(3))) unsigned int*)l, 16, 0, 0);
}

// ---------------------------------------------------------------------------
// MERGED prep. QKV weights (p<3) AND proj weights (p==3) emitted in
// FRAGMENT-TILED layout: (o,c) -> ((o>>4)*12+(c>>5))*512 + ((c>>3)&3)*128
// + (o&15)*8 + (c&7); an MFMA A-fragment is one coalesced dwordx4 at
// tilebase + lane*16 (no LDS staging in the GEMMs).
// ---------------------------------------------------------------------------
struct WSplitArgs {
  const float* w[4]; const float* g[4]; const float* be[4];
  const float* mu[4]; const float* va[4]; const float* bias;
};
__global__ __launch_bounds__(256) void prep(
    WSplitArgs a, _Float16* __restrict__ wsp16, __bf16* __restrict__ wspb,
    float* __restrict__ shv, const float* __restrict__ x,
    _Float16* __restrict__ xs) {
  __shared__ float tile[49 * 130];
  const int bx = blockIdx.x;
  const int tid = threadIdx.x;
  if (bx < 2304) {
    const int i = bx * 256 + tid;                 // < 589824
    const int p = i / WSZ, r = i - p * WSZ;
    const int o = r / Cn, cc = r - o * Cn;
    const float iv = a.g[p][o] / sqrtf(a.va[p][o] + 1e-5f);
    const float wv = a.w[p][r] * iv;
    const int toff = ((o >> 4) * 12 + (cc >> 5)) * 512 +
                     (((cc >> 3) & 3) << 7) + ((o & 15) << 3) + (cc & 7);
    if (p < 3) {
      _Float16 h, l;
      split2h(wv, h, l);
      wsp16[(size_t)(p * 2 + 0) * WSZ + toff] = h;
      wsp16[(size_t)(p * 2 + 1) * WSZ + toff] = l;
    } else {
      __bf16 h, m, l;
      split3(wv, h, m, l);
      wspb[(size_t)0 * WSZ + toff] = h;
      wspb[(size_t)1 * WSZ + toff] = m;
      wspb[(size_t)2 * WSZ + toff] = l;
    }
    if (cc == 0) {
      float sh = a.be[p][o] - a.mu[p][o] * iv;
      if (p == 3) sh += a.bias[o] * iv;
      shv[p * Cn + o] = sh;
    }
    return;
  }
  const int bid2 = bx - 2304;                     // < 1536
  const int t = bid2 & 3, b = (bid2 >> 2) & 31, zz = bid2 >> 7;
  const int ct = zz >> 2, nch = zz & 3;
  const int c0 = ct * 128, n0 = nch * 49;
  for (int idx = tid; idx < 49 * 128; idx += 256) {
    const int n = idx % 49, c = idx / 49;
    tile[n * 130 + c] = x[(size_t)t * BCNn + (size_t)b * CNn +
                          (size_t)(c0 + c) * Nn + n0 + n];
  }
  __syncthreads();
  for (int idx = tid; idx < 49 * 64; idx += 256) {
    const int cp = idx & 63, n = idx >> 6;
    const float v0 = tile[n * 130 + cp * 2];
    const float v1 = tile[n * 130 + cp * 2 + 1];
    _Float16 h0, l0, h1, l1;
    split2h(v0, h0, l0);
    split2h(v1, h1, l1);
    const size_t col = (size_t)t * NCOLS + (size_t)b * Nn + n0 + n;
    union { _Float16 f[2]; u32 u; } uh, ul;
    uh.f[0] = h0; uh.f[1] = h1;
    ul.f[0] = l0; ul.f[1] = l1;
    ((u32*)(xs + col * Cn + c0))[cp] = uh.u;
    ((u32*)(xs + (size_t)TBCNn + col * Cn + c0))[cp] = ul.u;
  }
}

// ---------------------------------------------------------------------------
// FUSED QKV GEMM + LIF(1.0) + bitpack, v5c: identical to validated v5b
// except __launch_bounds__(256, 3). The R10/R11 A-direct work cut LDS
// 72->40 KB, so 3 blocks/CU now fit (120 KB LDS, VGPR cap 170 >= 116):
// tail 1.72->1.15 rounds, 12 waves/CU for latency hiding.
// ---------------------------------------------------------------------------
__global__ __launch_bounds__(256, 3) void gemm_qkv_lif(
    const _Float16* __restrict__ xs,    // [2][t][col][c] f16 pre-split
    const _Float16* __restrict__ wsp16, // [3][2] fragment-tiled iv-scaled f16
    const float* __restrict__ shv,      // [4][o]
    u32* __restrict__ bq, u32* __restrict__ bk, u32* __restrict__ bv)
{
  __shared__ _Float16 Bsw[5][2][64][32];    // B ring: slot g%5, 8KB each
  const int orig = blockIdx.x;
  const int xcd = orig & 7, i8 = orig >> 3;
  const int wgid = xcd * 110 + (xcd < 2 ? xcd : 2) + i8;
  const int colt = wgid / 9, v = wgid - colt * 9;
  const int col0 = colt * 64;
  const int p = v / 3, mt = v - p * 3;
  const int o0 = mt * 128;
  const int tid = threadIdx.x, lane = tid & 63, wid = tid >> 6;
  const int wm = wid >> 1, wn = wid & 1;
  const int quad = lane >> 4, nl = lane & 15;
  u32* __restrict__ bits = (p == 0) ? bq : (p == 1) ? bk : bv;

  u32 afOff[2][4];
#pragma unroll
  for (int s = 0; s < 2; ++s)
#pragma unroll
    for (int mi = 0; mi < 4; ++mi)
      afOff[s][mi] = (u32)((((p * 2 + s) * WSZ) +
                            (mt * 8 + wm * 4 + mi) * 6144) * 2) +
                     (u32)(lane * 16);
  u32 bOff[2];
#pragma unroll
  for (int i = 0; i < 2; ++i) {
    const int c = i * 256 + wid * 64 + lane;     // B chunk 0..511
    const int s = c >> 8, rem = c & 255, row = rem >> 2, kb = rem & 3;
    const int kbs = kb ^ ((row >> 1) & 3);
    bOff[i] = (u32)(((size_t)s * TBCNn + (size_t)(col0 + row) * Cn + kbs * 8) * 2);
  }
  const char* wB = (const char*)wsp16;
  const char* xB = (const char*)xs;
  char* bD0 = (char*)&Bsw[0][0][0][0] + wid * 1024;

#define STAGE_B(g_) do {                                                   \
    const int t_ = ((g_) / 24) * 2 + ((g_) & 1);                           \
    const int kk_ = (((g_) % 24) >> 1);                                    \
    const u32 bk_ = (u32)(kk_ * 64) + (u32)t_ * (u32)(NCOLS * Cn * 2);     \
    char* d_ = bD0 + ((g_) % 5) * 8192;                                    \
    _Pragma("unroll") for (int i_ = 0; i_ < 2; ++i_)                       \
      gl_lds16(xB + bOff[i_] + bk_, d_ + i_ * 4096);                       \
  } while (0)
#define LOAD_AF(DST, g_) do {                                              \
    const u32 ak2_ = (u32)(((g_) % 12) * 1024);                            \
    _Pragma("unroll") for (int s_ = 0; s_ < 2; ++s_)                       \
    _Pragma("unroll") for (int m_ = 0; m_ < 4; ++m_)                       \
      DST[s_][m_] = *(const f16x8*)(wB + afOff[s_][m_] + ak2_);            \
  } while (0)

  f32x4 sh_[4];
#pragma unroll
  for (int mi = 0; mi < 4; ++mi)
    sh_[mi] = *(const f32x4*)&shv[p * Cn + o0 + wm * 64 + mi * 16 + quad * 4];

  f32x4 acc0[4][2], acc1[4][2];
  f32x4 vst[4][2] = {};
  f16x8 afA[2][4], afB[2][4];

  auto epi = [&](f32x4 (&ac)[4][2], int t) {
#pragma unroll
    for (int ni = 0; ni < 2; ++ni) {
      u32 w0 = 0, w1 = 0;
#pragma unroll
      for (int mi = 0; mi < 4; ++mi) {
#pragma unroll
        for (int r = 0; r < 4; ++r) {
          const float y = ac[mi][ni][r] + sh_[mi][r];
          const float vv = vst[mi][ni][r];
          const float nv = vv + (y - vv) * 0.5f;
          const bool sk = nv >= 1.0f;
          vst[mi][ni][r] = sk ? 0.f : nv;
          const u32 b1 = sk ? 1u : 0u;
          const int pos = ((mi & 1) << 4) + (quad << 2) + r;
          if (mi < 2) w0 |= b1 << pos; else w1 |= b1 << pos;
        }
      }
      w0 |= __shfl_xor(w0, 16); w0 |= __shfl_xor(w0, 32);
      w1 |= __shfl_xor(w1, 16); w1 |= __shfl_xor(w1, 32);
      if (quad == 0) {
        const int col = col0 + wn * 32 + ni * 16 + nl;
        const int bb = col / Nn, nn = col - bb * Nn;
        u32* bp = bits + (size_t)t * BHNn +
                  ((size_t)bb * Hn + (mt * 4 + wm * 2)) * Nn + nn;
        bp[0] = w0;
        bp[Nn] = w1;
      }
    }
  };

  auto sub = [&](f16x8 (&afc)[2][4], f16x8 (&afn)[2][4], int g) {
    const int kk = g % 12;
    const int be = (2 * g) % 5, bo = (2 * g + 1) % 5;
    // ===== even sub-step (t = (g/12)*2) =====
    if (g == 0)       asm volatile("s_waitcnt vmcnt(14)" ::: "memory");
    else if (g == 23) asm volatile("s_waitcnt vmcnt(18)" ::: "memory");
    else              asm volatile("s_waitcnt vmcnt(22)" ::: "memory");
    __builtin_amdgcn_s_barrier();
    __builtin_amdgcn_sched_barrier(0);
    if (g < 22) STAGE_B(2 * g + 4);          // Be(g+2)
    __builtin_amdgcn_sched_barrier(0);
    if (kk == 0) {
#pragma unroll
      for (int mi = 0; mi < 4; ++mi)
#pragma unroll
        for (int ni = 0; ni < 2; ++ni) {
          acc0[mi][ni] = f32x4{0.f, 0.f, 0.f, 0.f};
          acc1[mi][ni] = f32x4{0.f, 0.f, 0.f, 0.f};
        }
    }
    {
      f16x8 bfr[2][2];
#pragma unroll
      for (int i = 0; i < 2; ++i) {
        const int rb = wn * 32 + i * 16 + nl;
        const int kb2 = (quad ^ ((rb >> 1) & 3)) * 8;
        bfr[0][i] = *(const f16x8*)&Bsw[be][0][rb][kb2];
        bfr[1][i] = *(const f16x8*)&Bsw[be][1][rb][kb2];
      }
      __builtin_amdgcn_s_setprio(1);
#pragma unroll
      for (int mi = 0; mi < 4; ++mi)
#pragma unroll
        for (int ni = 0; ni < 2; ++ni) {
          f32x4 c = acc0[mi][ni];
          c = __builtin_amdgcn_mfma_f32_16x16x32_f16(afc[0][mi], bfr[0][ni], c, 0, 0, 0);
          c = __builtin_amdgcn_mfma_f32_16x16x32_f16(afc[0][mi], bfr[1][ni], c, 0, 0, 0);
          c = __builtin_amdgcn_mfma_f32_16x16x32_f16(afc[1][mi], bfr[0][ni], c, 0, 0, 0);
          acc0[mi][ni] = c;
        }
      __builtin_amdgcn_s_setprio(0);
    }
    // ===== odd sub-step (t = (g/12)*2+1, reuses afc) =====
    if (g == 22)      asm volatile("s_waitcnt vmcnt(12)" ::: "memory");
    else if (g == 23) asm volatile("s_waitcnt vmcnt(8)"  ::: "memory");
    else              asm volatile("s_waitcnt vmcnt(14)" ::: "memory");
    __builtin_amdgcn_s_barrier();
    __builtin_amdgcn_sched_barrier(0);
    if (g < 23) LOAD_AF(afn, g + 1);         // af(g+1), ahead of B stages
    __builtin_amdgcn_sched_barrier(0);
    if (g < 22) STAGE_B(2 * g + 5);          // Bo(g+2)
    __builtin_amdgcn_sched_barrier(0);
    {
      f16x8 bfr[2][2];
#pragma unroll
      for (int i = 0; i < 2; ++i) {
        const int rb = wn * 32 + i * 16 + nl;
        const int kb2 = (quad ^ ((rb >> 1) & 3)) * 8;
        bfr[0][i] = *(const f16x8*)&Bsw[bo][0][rb][kb2];
        bfr[1][i] = *(const f16x8*)&Bsw[bo][1][rb][kb2];
      }
      __builtin_amdgcn_s_setprio(1);
#pragma unroll
      for (int mi = 0; mi < 4; ++mi)
#pragma unroll
        for (int ni = 0; ni < 2; ++ni) {
          f32x4 c = acc1[mi][ni];
          c = __builtin_amdgcn_mfma_f32_16x16x32_f16(afc[0][mi], bfr[0][ni], c, 0, 0, 0);
          c = __builtin_amdgcn_mfma_f32_16x16x32_f16(afc[0][mi], bfr[1][ni], c, 0, 0, 0);
          c = __builtin_amdgcn_mfma_f32_16x16x32_f16(afc[1][mi], bfr[0][ni], c, 0, 0, 0);
          acc1[mi][ni] = c;
        }
      __builtin_amdgcn_s_setprio(0);
    }
    if (kk == 11) {
      const int p2 = g / 12;
      epi(acc0, p2 * 2 + 0);
      epi(acc1, p2 * 2 + 1);
    }
  };

  // prologue FIFO order: Be(0)2, Bo(0)2, Be(1)2, af(0)8, Bo(1)2
  STAGE_B(0); STAGE_B(1); STAGE_B(2);
  LOAD_AF(afA, 0);
  STAGE_B(3);

#pragma unroll 1
  for (int gp = 0; gp < 12; ++gp) {
    sub(afA, afB, 2 * gp);
    sub(afB, afA, 2 * gp + 1);
  }
#undef STAGE_B
#undef LOAD_AF
}

// ---------------------------------------------------------------------------
// FUSED attention + LIF(0.5), v3 factorized (UNCHANGED from R9: validated).
// ---------------------------------------------------------------------------
#define USTR 232
#define GSTR 40
__global__ __launch_bounds__(256, 2) void attn_lif(
    const u32* __restrict__ qb, const u32* __restrict__ kb,
    const u32* __restrict__ vb, const float* __restrict__ policy,
    __bf16* __restrict__ sp) {
  __shared__ u32 qs[208], ks[224], vs_[224];
  __shared__ float ps[224];
  __shared__ __bf16 psp[3][224];
  __shared__ __bf16 Ul[3][32][USTR];   // U^T: [d][m]
  __shared__ __bf16 GT[3][32][GSTR];   // G^T: [d][c]
  const int bh = blockIdx.x;           // b*H + h
  const int bN = bh / Hn;
  const int h = bh - bN * Hn;
  const int tid = threadIdx.x;
  const int lane = tid & 63, wid = tid >> 6;
  const int quad = lane >> 4, nl = lane & 15;
  const int wm1 = wid >> 1, wn1 = wid & 1;
  const __bf16 one = (__bf16)1.0f, zero = (__bf16)0.0f;

  float vst[4][2][4] = {};

  for (int t = 0; t < Tn; ++t) {
    const int tb = t * Bn + bN;
    const int gid = tb * Hn + h;
    if (t) __syncthreads();
    for (int i = tid; i < 224; i += 256) {
      const bool in = i < Nn;
      if (i < 208) qs[i] = in ? qb[(size_t)gid * Nn + i] : 0u;
      ks[i] = in ? kb[(size_t)gid * Nn + i] : 0u;
      vs_[i] = in ? vb[(size_t)gid * Nn + i] : 0u;
      const float p = in ? policy[(size_t)tb * Nn + i] : 0.f;
      ps[i] = p;
      __bf16 hh, mm, ll;
      split3(p, hh, mm, ll);
      psp[0][i] = hh; psp[1][i] = mm; psp[2][i] = ll;
    }
    __syncthreads();

#pragma unroll
    for (int it = 0; it < 7; ++it) {
      const int idx = tid + it * 256;
      const int d = idx & 31, mg = idx >> 5;
      __bf16 u4[3][4];
#pragma unroll
      for (int j = 0; j < 4; ++j) {
        const int m = mg * 4 + j;
        const bool bit = (vs_[m] >> d) & 1u;
#pragma unroll
        for (int s = 0; s < 3; ++s)
          u4[s][j] = bit ? psp[s][m] : zero;
      }
#pragma unroll
      for (int s = 0; s < 3; ++s)
        *(bf16x4v*)&Ul[s][d][mg * 4] = *(bf16x4v*)u4[s];
    }
    __syncthreads();

    f32x4 gacc = {0.f, 0.f, 0.f, 0.f};
    const int crow = wm1 * 16 + nl;
    const int drow = wn1 * 16 + nl;
#pragma unroll
    for (int slab = 0; slab < 7; ++slab) {
      const int m0 = slab * 32 + quad * 8;
      u32 kw[8];
      *(uint4*)&kw[0] = *(const uint4*)&ks[m0];
      *(uint4*)&kw[4] = *(const uint4*)&ks[m0 + 4];
      __bf16 a8[8];
#pragma unroll
      for (int j = 0; j < 8; ++j)
        a8[j] = ((kw[j] >> crow) & 1u) ? one : zero;
      const bf16x8 af = *(const bf16x8*)a8;
#pragma unroll
      for (int s = 0; s < 3; ++s)
        gacc = __builtin_amdgcn_mfma_f32_16x16x32_bf16(
            af, *(const bf16x8*)&Ul[s][drow][slab * 32 + quad * 8], gacc, 0, 0, 0);
    }
#pragma unroll
    for (int r = 0; r < 4; ++r) {
      __bf16 gh, gm, gl;
      split3(gacc[r], gh, gm, gl);
      const int cc = wm1 * 16 + quad * 4 + r;
      GT[0][drow][cc] = gh;
      GT[1][drow][cc] = gm;
      GT[2][drow][cc] = gl;
    }
    __syncthreads();

    bf16x8 bfr2[3][2];
#pragma unroll
    for (int s = 0; s < 3; ++s)
#pragma unroll
      for (int nt = 0; nt < 2; ++nt)
        bfr2[s][nt] = *(const bf16x8*)&GT[s][nt * 16 + nl][quad * 8];

    f32x4 acc2[4][2] = {};
#pragma unroll
    for (int mi = 0; mi < 4; ++mi) {
      const int lt = wid + mi * 4;
      if (lt < 13) {
        const u32 qw = qs[lt * 16 + nl];
        __bf16 a8[8];
#pragma unroll
        for (int j = 0; j < 8; ++j)
          a8[j] = ((qw >> (quad * 8 + j)) & 1u) ? one : zero;
        const bf16x8 af2 = *(const bf16x8*)a8;
#pragma unroll
        for (int nt = 0; nt < 2; ++nt) {
          f32x4 c = acc2[mi][nt];
          c = __builtin_amdgcn_mfma_f32_16x16x32_bf16(af2, bfr2[0][nt], c, 0, 0, 0);
          c = __builtin_amdgcn_mfma_f32_16x16x32_bf16(af2, bfr2[1][nt], c, 0, 0, 0);
          c = __builtin_amdgcn_mfma_f32_16x16x32_bf16(af2, bfr2[2][nt], c, 0, 0, 0);
          acc2[mi][nt] = c;
        }
      }
    }
#pragma unroll
    for (int mi = 0; mi < 4; ++mi) {
      const int lt = wid + mi * 4;
      if (lt >= 13) continue;
#pragma unroll
      for (int r = 0; r < 4; ++r) {
        const int n = lt * 16 + quad * 4 + r;
        if (n >= Nn) continue;
        const float ann = (float)__popc(qs[n] & ks[n]);
        const float wd = ann * (1.0f - ps[n]);
        const u32 vn = vs_[n];
        __bf16* op = sp + (size_t)t * BCNn + ((size_t)bN * Nn + n) * Cn + h * 32;
#pragma unroll
        for (int nt = 0; nt < 2; ++nt) {
          const int d = nt * 16 + nl;
          const float bit = (float)((vn >> d) & 1u);
          const float y = (acc2[mi][nt][r] + wd * bit) * 0.25f;
          const float vv = vst[mi][nt][r];
          const float nv = vv + (y - vv) * 0.5f;
          const bool s = nv >= 0.5f;
          vst[mi][nt][r] = s ? 0.f : nv;
          op[d] = (__bf16)(s ? 1.0f : 0.0f);
        }
      }
    }
  }
}

// ---------------------------------------------------------------------------
// FUSED proj GEMM + LIF(1.0) -> out, v2 (UNCHANGED from R11: validated).
// ---------------------------------------------------------------------------
__global__ __launch_bounds__(256, 3) void gemm_proj_lif(
    const __bf16* __restrict__ sp, const __bf16* __restrict__ wspb,
    const float* __restrict__ shv, float* __restrict__ out)
{
  __shared__ __bf16 Bsw[5][64][32];      // B ring: slot g%5, 4KB each
  const int orig = blockIdx.x;
  const int xcd = orig & 7, i8 = orig >> 3;
  const int wgid = xcd * 73 + (xcd < 4 ? xcd : 4) + i8;
  const int colt = wgid / 6, ot = wgid - colt * 6;
  const int col0 = colt * 64;
  const int o0 = ot * 64;
  const int tid = threadIdx.x, lane = tid & 63, wid = tid >> 6;
  const int wm = wid >> 1, wn = wid & 1;
  const int quad = lane >> 4, nl = lane & 15;

  u32 afOff[3][2];
#pragma unroll
  for (int s = 0; s < 3; ++s)
#pragma unroll
    for (int mi = 0; mi < 2; ++mi)
      afOff[s][mi] = (u32)(((s * WSZ) + (ot * 4 + wm * 2 + mi) * 6144) * 2) +
                     (u32)(lane * 16);
  u32 bOff;
  {
    const int c = wid * 64 + lane;               // B chunk 0..255
    const int row = c >> 2, kb = c & 3;
    const int kbs = kb ^ ((row >> 1) & 3);
    bOff = (u32)(((size_t)(col0 + row) * Cn + kbs * 8) * 2);
  }
  const char* wB = (const char*)wspb;
  const char* sB = (const char*)sp;
  char* bD0 = (char*)&Bsw[0][0][0] + wid * 1024;

#define STAGE_B(g_) do {                                                   \
    const int t_ = ((g_) / 24) * 2 + ((g_) & 1);                           \
    const int kk_ = (((g_) % 24) >> 1);                                    \
    const u32 bk_ = (u32)(kk_ * 64) + (u32)t_ * (u32)(BCNn * 2);           \
    gl_lds16(sB + bOff + bk_, bD0 + ((g_) % 5) * 4096);                    \
  } while (0)
#define LOAD_AF(DST, g_) do {                                              \
    const u32 ak2_ = (u32)(((g_) % 12) * 1024);                            \
    _Pragma("unroll") for (int s_ = 0; s_ < 3; ++s_)                       \
    _Pragma("unroll") for (int m_ = 0; m_ < 2; ++m_)                       \
      DST[s_][m_] = *(const bf16x8*)(wB + afOff[s_][m_] + ak2_);           \
  } while (0)

  f32x4 sh_[2];
#pragma unroll
  for (int mi = 0; mi < 2; ++mi)
    sh_[mi] = *(const f32x4*)&shv[3 * Cn + o0 + wm * 32 + mi * 16 + quad * 4];

  f32x4 acc0[2][2], acc1[2][2];
  f32x4 vst[2][2] = {};   // LIF(1.0) membrane, persists across t
  bf16x8 afA[3][2], afB[3][2];

  auto epi = [&](f32x4 (&ac)[2][2], int t) {
#pragma unroll
    for (int mi = 0; mi < 2; ++mi) {
      const int ob = o0 + wm * 32 + mi * 16 + quad * 4;
#pragma unroll
      for (int ni = 0; ni < 2; ++ni) {
        const int col = col0 + wn * 32 + ni * 16 + nl;
        const int bb = col / Nn, nn = col - bb * Nn;
        float* op = out + (size_t)t * BCNn + (size_t)bb * CNn + nn;
#pragma unroll
        for (int r = 0; r < 4; ++r) {
          const float y = ac[mi][ni][r] + sh_[mi][r];
          const float vv = vst[mi][ni][r];
          const float nv = vv + (y - vv) * 0.5f;
          const bool sk = nv >= 1.0f;
          vst[mi][ni][r] = sk ? 0.f : nv;
          op[(size_t)(ob + r) * Nn] = sk ? 1.0f : 0.0f;
        }
      }
    }
  };

  auto sub = [&](bf16x8 (&afc)[3][2], bf16x8 (&afn)[3][2], int g) {
    const int kk = g % 12;
    const int be = (2 * g) % 5, bo = (2 * g + 1) % 5;
    // ===== even sub-step (t = (g/12)*2) =====
    if (g == 23) asm volatile("s_waitcnt vmcnt(0)" ::: "memory");
    else         asm volatile("s_waitcnt vmcnt(1)" ::: "memory");
    __builtin_amdgcn_s_barrier();
    __builtin_amdgcn_sched_barrier(0);
    if (g < 22) STAGE_B(2 * g + 4);          // Be(g+2)
    __builtin_amdgcn_sched_barrier(0);
    if (kk == 0) {
#pragma unroll
      for (int mi = 0; mi < 2; ++mi)
#pragma unroll
        for (int ni = 0; ni < 2; ++ni) {
          acc0[mi][ni] = f32x4{0.f, 0.f, 0.f, 0.f};
          acc1[mi][ni] = f32x4{0.f, 0.f, 0.f, 0.f};
        }
    }
    {
      bf16x8 bfr[2];
#pragma unroll
      for (int ni = 0; ni < 2; ++ni) {
        const int rb = wn * 32 + ni * 16 + nl;
        const int kb2 = (quad ^ ((rb >> 1) & 3)) * 8;
        bfr[ni] = *(const bf16x8*)&Bsw[be][rb][kb2];
      }
      __builtin_amdgcn_s_setprio(1);
#pragma unroll
      for (int mi = 0; mi < 2; ++mi)
#pragma unroll
        for (int ni = 0; ni < 2; ++ni) {
          f32x4 c = acc0[mi][ni];
          c = __builtin_amdgcn_mfma_f32_16x16x32_bf16(afc[0][mi], bfr[ni], c, 0, 0, 0);
          c = __builtin_amdgcn_mfma_f32_16x16x32_bf16(afc[1][mi], bfr[ni], c, 0, 0, 0);
          c = __builtin_amdgcn_mfma_f32_16x16x32_bf16(afc[2][mi], bfr[ni], c, 0, 0, 0);
          acc0[mi][ni] = c;
        }
      __builtin_amdgcn_s_setprio(0);
    }
    // ===== odd sub-step (t = (g/12)*2+1, reuses afc) =====
    if (g == 22)      asm volatile("s_waitcnt vmcnt(1)" ::: "memory");
    else if (g == 23) asm volatile("s_waitcnt vmcnt(0)" ::: "memory");
    else              asm volatile("s_waitcnt vmcnt(2)" ::: "memory");
    __builtin_amdgcn_s_barrier();
    __builtin_amdgcn_sched_barrier(0);
    if (g < 23) LOAD_AF(afn, g + 1);         // af(g+1)
    __builtin_amdgcn_sched_barrier(0);
    if (g < 22) STAGE_B(2 * g + 5);          // Bo(g+2)
    __builtin_amdgcn_sched_barrier(0);
    {
      bf16x8 bfr[2];
#pragma unroll
      for (int ni = 0; ni < 2; ++ni) {
        const int rb = wn * 32 + ni * 16 + nl;
        const int kb2 = (quad ^ ((rb >> 1) & 3)) * 8;
        bfr[ni] = *(const bf16x8*)&Bsw[bo][rb][kb2];
      }
      __builtin_amdgcn_s_setprio(1);
#pragma unroll
      for (int mi = 0; mi < 2; ++mi)
#pragma unroll
        for (int ni = 0; ni < 2; ++ni) {
          f32x4 c = acc1[mi][ni];
          c = __builtin_amdgcn_mfma_f32_16x16x32_bf16(afc[0][mi], bfr[ni], c, 0, 0, 0);
          c = __builtin_amdgcn_mfma_f32_16x16x32_bf16(afc[1][mi], bfr[ni], c, 0, 0, 0);
          c = __builtin_amdgcn_mfma_f32_16x16x32_bf16(afc[2][mi], bfr[ni], c, 0, 0, 0);
          acc1[mi][ni] = c;
        }
      __builtin_amdgcn_s_setprio(0);
    }
    if (kk == 11) {
      const int p2 = g / 12;
      epi(acc0, p2 * 2 + 0);
      epi(acc1, p2 * 2 + 1);
    }
  };

  // prologue FIFO: B0, B1, B2, af0(6), B3  -> slots 0,1,2,-,3 (distinct)
  STAGE_B(0); STAGE_B(1); STAGE_B(2);
  LOAD_AF(afA, 0);
  STAGE_B(3);

#pragma unroll 1
  for (int gp = 0; gp < 12; ++gp) {
    sub(afA, afB, 2 * gp);
    sub(afB, afA, 2 * gp + 1);
  }
#undef STAGE_B
#undef LOAD_AF
}

// ===========================================================================
extern "C" void kernel_launch(void* const* d_in, const int* in_sizes, int n_in,
                              void* d_out, int out_size, void* d_ws, size_t ws_size,
                              hipStream_t stream) {
  const float* x      = (const float*)d_in[0];
  const float* policy = (const float*)d_in[1];
  const float* qw = (const float*)d_in[2];
  const float* qg = (const float*)d_in[3];
  const float* qb_ = (const float*)d_in[4];
  const float* qm = (const float*)d_in[5];
  const float* qv = (const float*)d_in[6];
  const float* kw = (const float*)d_in[7];
  const float* kg = (const float*)d_in[8];
  const float* kbe = (const float*)d_in[9];
  const float* km = (const float*)d_in[10];
  const float* kv = (const float*)d_in[11];
  const float* vw = (const float*)d_in[12];
  const float* vg = (const float*)d_in[13];
  const float* vbe = (const float*)d_in[14];
  const float* vm = (const float*)d_in[15];
  const float* vv = (const float*)d_in[16];
  const float* pw = (const float*)d_in[17];
  const float* pg = (const float*)d_in[18];
  const float* pbe = (const float*)d_in[19];
  const float* pm = (const float*)d_in[20];
  const float* pv = (const float*)d_in[21];
  const float* pbias = (const float*)d_in[22];
  float* out = (float*)d_out;

  char* base = (char*)d_ws;
  _Float16* xs   = (_Float16*)base;                               // 38,535,168
  _Float16* wsp16 = (_Float16*)(base + (size_t)TBCNn * 4);        //  1,769,472
  __bf16* wspb   = (__bf16*)((char*)wsp16 + (size_t)6 * WSZ * 2); //    884,736
  float* shv     = (float*)((char*)wspb + (size_t)3 * WSZ * 2);   //      6,144
  u32* bq        = (u32*)((char*)shv + 4 * Cn * 4);               //  1,204,224 x3
  u32* bk = bq + PBITS;
  u32* bv = bk + PBITS;
  __bf16* sp     = (__bf16*)(bv + PBITS);                         // 19,267,584

  WSplitArgs wa;
  wa.w[0] = qw; wa.g[0] = qg; wa.be[0] = qb_; wa.mu[0] = qm; wa.va[0] = qv;
  wa.w[1] = kw; wa.g[1] = kg; wa.be[1] = kbe; wa.mu[1] = km; wa.va[1] = kv;
  wa.w[2] = vw; wa.g[2] = vg; wa.be[2] = vbe; wa.mu[2] = vm; wa.va[2] = vv;
  wa.w[3] = pw; wa.g[3] = pg; wa.be[3] = pbe; wa.mu[3] = pm; wa.va[3] = pv;
  wa.bias = pbias;
  prep<<<3840, 256, 0, stream>>>(wa, wsp16, wspb, shv, x, xs);

  gemm_qkv_lif<<<882, 256, 0, stream>>>(xs, wsp16, shv, bq, bk, bv);
  attn_lif<<<Bn * Hn, 256, 0, stream>>>(bq, bk, bv, policy, sp);
  gemm_proj_lif<<<588, 256, 0, stream>>>(sp, wspb, shv, out);
}

// Round 13
// 275.999 us; speedup vs baseline: 1.7714x; 1.7714x over previous
//
#include <hip/hip_runtime.h>

typedef unsigned int u32;
typedef __bf16 bf16x8 __attribute__((ext_vector_type(8)));
typedef __bf16 bf16x4v __attribute__((ext_vector_type(4)));
typedef _Float16 f16x8 __attribute__((ext_vector_type(8)));
typedef float f32x4 __attribute__((ext_vector_type(4)));

#define Tn 4
#define Bn 32
#define Cn 384
#define Nn 196
#define Hn 12
#define CNn (Cn*Nn)         // 75264
#define BCNn (Bn*CNn)       // 2408448
#define BHNn (Bn*Hn*Nn)     // 75264
#define PBITS (Tn*BHNn)     // 301056
#define TBCNn (Tn*BCNn)     // 9633792
#define NCOLS 6272          // B*N
#define WSZ 147456          // 384*384

// fp32 -> 3-way bf16 split (residual ~2^-24 rel)
__device__ __forceinline__ void split3(float v, __bf16& h, __bf16& m, __bf16& l) {
  h = (__bf16)v;  float r = v - (float)h;
  m = (__bf16)r;  float r2 = r - (float)m;
  l = (__bf16)r2;
}
// fp32 -> 2-way f16 split (residual ~2^-22 rel)
__device__ __forceinline__ void split2h(float v, _Float16& h, _Float16& l) {
  h = (_Float16)v;  l = (_Float16)(v - (float)h);
}

// direct global->LDS 16B copy: lane i lands at ldsbase + i*16 (wave-uniform base)
__device__ __forceinline__ void gl_lds16(const void* g, void* l) {
  __builtin_amdgcn_global_load_lds(
      (const __attribute__((address_space(1))) unsigned int*)g,
      (__attribute__((address_space(3))) unsigned int*)l, 16, 0, 0);
}

// ---------------------------------------------------------------------------
// MERGED prep. QKV weights (p<3) AND proj weights (p==3) emitted in
// FRAGMENT-TILED layout: (o,c) -> ((o>>4)*12+(c>>5))*512 + ((c>>3)&3)*128
// + (o&15)*8 + (c&7); an MFMA A-fragment is one coalesced dwordx4 at
// tilebase + lane*16 (no LDS staging in the GEMMs).
// ---------------------------------------------------------------------------
struct WSplitArgs {
  const float* w[4]; const float* g[4]; const float* be[4];
  const float* mu[4]; const float* va[4]; const float* bias;
};
__global__ __launch_bounds__(256) void prep(
    WSplitArgs a, _Float16* __restrict__ wsp16, __bf16* __restrict__ wspb,
    float* __restrict__ shv, const float* __restrict__ x,
    _Float16* __restrict__ xs) {
  __shared__ float tile[49 * 130];
  const int bx = blockIdx.x;
  const int tid = threadIdx.x;
  if (bx < 2304) {
    const int i = bx * 256 + tid;                 // < 589824
    const int p = i / WSZ, r = i - p * WSZ;
    const int o = r / Cn, cc = r - o * Cn;
    const float iv = a.g[p][o] / sqrtf(a.va[p][o] + 1e-5f);
    const float wv = a.w[p][r] * iv;
    const int toff = ((o >> 4) * 12 + (cc >> 5)) * 512 +
                     (((cc >> 3) & 3) << 7) + ((o & 15) << 3) + (cc & 7);
    if (p < 3) {
      _Float16 h, l;
      split2h(wv, h, l);
      wsp16[(size_t)(p * 2 + 0) * WSZ + toff] = h;
      wsp16[(size_t)(p * 2 + 1) * WSZ + toff] = l;
    } else {
      __bf16 h, m, l;
      split3(wv, h, m, l);
      wspb[(size_t)0 * WSZ + toff] = h;
      wspb[(size_t)1 * WSZ + toff] = m;
      wspb[(size_t)2 * WSZ + toff] = l;
    }
    if (cc == 0) {
      float sh = a.be[p][o] - a.mu[p][o] * iv;
      if (p == 3) sh += a.bias[o] * iv;
      shv[p * Cn + o] = sh;
    }
    return;
  }
  const int bid2 = bx - 2304;                     // < 1536
  const int t = bid2 & 3, b = (bid2 >> 2) & 31, zz = bid2 >> 7;
  const int ct = zz >> 2, nch = zz & 3;
  const int c0 = ct * 128, n0 = nch * 49;
  for (int idx = tid; idx < 49 * 128; idx += 256) {
    const int n = idx % 49, c = idx / 49;
    tile[n * 130 + c] = x[(size_t)t * BCNn + (size_t)b * CNn +
                          (size_t)(c0 + c) * Nn + n0 + n];
  }
  __syncthreads();
  for (int idx = tid; idx < 49 * 64; idx += 256) {
    const int cp = idx & 63, n = idx >> 6;
    const float v0 = tile[n * 130 + cp * 2];
    const float v1 = tile[n * 130 + cp * 2 + 1];
    _Float16 h0, l0, h1, l1;
    split2h(v0, h0, l0);
    split2h(v1, h1, l1);
    const size_t col = (size_t)t * NCOLS + (size_t)b * Nn + n0 + n;
    union { _Float16 f[2]; u32 u; } uh, ul;
    uh.f[0] = h0; uh.f[1] = h1;
    ul.f[0] = l0; ul.f[1] = l1;
    ((u32*)(xs + col * Cn + c0))[cp] = uh.u;
    ((u32*)(xs + (size_t)TBCNn + col * Cn + c0))[cp] = ul.u;
  }
}

// ---------------------------------------------------------------------------
// FUSED QKV GEMM + LIF(1.0) + bitpack, v5b (EXACT R11 revert, validated
// 81us). R12's (256,3) hint made the allocator spill acc/af to scratch
// (VGPR 116->84, +540MB scratch traffic, 317us). launch_bounds stays (256,2):
// the hint cannot raise runtime occupancy anyway (residency follows emitted
// VGPR/LDS), it can only constrain the allocator.
// ---------------------------------------------------------------------------
__global__ __launch_bounds__(256, 2) void gemm_qkv_lif(
    const _Float16* __restrict__ xs,    // [2][t][col][c] f16 pre-split
    const _Float16* __restrict__ wsp16, // [3][2] fragment-tiled iv-scaled f16
    const float* __restrict__ shv,      // [4][o]
    u32* __restrict__ bq, u32* __restrict__ bk, u32* __restrict__ bv)
{
  __shared__ _Float16 Bsw[5][2][64][32];    // B ring: slot g%5, 8KB each
  const int orig = blockIdx.x;
  const int xcd = orig & 7, i8 = orig >> 3;
  const int wgid = xcd * 110 + (xcd < 2 ? xcd : 2) + i8;
  const int colt = wgid / 9, v = wgid - colt * 9;
  const int col0 = colt * 64;
  const int p = v / 3, mt = v - p * 3;
  const int o0 = mt * 128;
  const int tid = threadIdx.x, lane = tid & 63, wid = tid >> 6;
  const int wm = wid >> 1, wn = wid & 1;
  const int quad = lane >> 4, nl = lane & 15;
  u32* __restrict__ bits = (p == 0) ? bq : (p == 1) ? bk : bv;

  u32 afOff[2][4];
#pragma unroll
  for (int s = 0; s < 2; ++s)
#pragma unroll
    for (int mi = 0; mi < 4; ++mi)
      afOff[s][mi] = (u32)((((p * 2 + s) * WSZ) +
                            (mt * 8 + wm * 4 + mi) * 6144) * 2) +
                     (u32)(lane * 16);
  u32 bOff[2];
#pragma unroll
  for (int i = 0; i < 2; ++i) {
    const int c = i * 256 + wid * 64 + lane;     // B chunk 0..511
    const int s = c >> 8, rem = c & 255, row = rem >> 2, kb = rem & 3;
    const int kbs = kb ^ ((row >> 1) & 3);
    bOff[i] = (u32)(((size_t)s * TBCNn + (size_t)(col0 + row) * Cn + kbs * 8) * 2);
  }
  const char* wB = (const char*)wsp16;
  const char* xB = (const char*)xs;
  char* bD0 = (char*)&Bsw[0][0][0][0] + wid * 1024;

#define STAGE_B(g_) do {                                                   \
    const int t_ = ((g_) / 24) * 2 + ((g_) & 1);                           \
    const int kk_ = (((g_) % 24) >> 1);                                    \
    const u32 bk_ = (u32)(kk_ * 64) + (u32)t_ * (u32)(NCOLS * Cn * 2);     \
    char* d_ = bD0 + ((g_) % 5) * 8192;                                    \
    _Pragma("unroll") for (int i_ = 0; i_ < 2; ++i_)                       \
      gl_lds16(xB + bOff[i_] + bk_, d_ + i_ * 4096);                       \
  } while (0)
#define LOAD_AF(DST, g_) do {                                              \
    const u32 ak2_ = (u32)(((g_) % 12) * 1024);                            \
    _Pragma("unroll") for (int s_ = 0; s_ < 2; ++s_)                       \
    _Pragma("unroll") for (int m_ = 0; m_ < 4; ++m_)                       \
      DST[s_][m_] = *(const f16x8*)(wB + afOff[s_][m_] + ak2_);            \
  } while (0)

  f32x4 sh_[4];
#pragma unroll
  for (int mi = 0; mi < 4; ++mi)
    sh_[mi] = *(const f32x4*)&shv[p * Cn + o0 + wm * 64 + mi * 16 + quad * 4];

  f32x4 acc0[4][2], acc1[4][2];
  f32x4 vst[4][2] = {};
  f16x8 afA[2][4], afB[2][4];

  auto epi = [&](f32x4 (&ac)[4][2], int t) {
#pragma unroll
    for (int ni = 0; ni < 2; ++ni) {
      u32 w0 = 0, w1 = 0;
#pragma unroll
      for (int mi = 0; mi < 4; ++mi) {
#pragma unroll
        for (int r = 0; r < 4; ++r) {
          const float y = ac[mi][ni][r] + sh_[mi][r];
          const float vv = vst[mi][ni][r];
          const float nv = vv + (y - vv) * 0.5f;
          const bool sk = nv >= 1.0f;
          vst[mi][ni][r] = sk ? 0.f : nv;
          const u32 b1 = sk ? 1u : 0u;
          const int pos = ((mi & 1) << 4) + (quad << 2) + r;
          if (mi < 2) w0 |= b1 << pos; else w1 |= b1 << pos;
        }
      }
      w0 |= __shfl_xor(w0, 16); w0 |= __shfl_xor(w0, 32);
      w1 |= __shfl_xor(w1, 16); w1 |= __shfl_xor(w1, 32);
      if (quad == 0) {
        const int col = col0 + wn * 32 + ni * 16 + nl;
        const int bb = col / Nn, nn = col - bb * Nn;
        u32* bp = bits + (size_t)t * BHNn +
                  ((size_t)bb * Hn + (mt * 4 + wm * 2)) * Nn + nn;
        bp[0] = w0;
        bp[Nn] = w1;
      }
    }
  };

  auto sub = [&](f16x8 (&afc)[2][4], f16x8 (&afn)[2][4], int g) {
    const int kk = g % 12;
    const int be = (2 * g) % 5, bo = (2 * g + 1) % 5;
    // ===== even sub-step (t = (g/12)*2) =====
    if (g == 0)       asm volatile("s_waitcnt vmcnt(14)" ::: "memory");
    else if (g == 23) asm volatile("s_waitcnt vmcnt(18)" ::: "memory");
    else              asm volatile("s_waitcnt vmcnt(22)" ::: "memory");
    __builtin_amdgcn_s_barrier();
    __builtin_amdgcn_sched_barrier(0);
    if (g < 22) STAGE_B(2 * g + 4);          // Be(g+2)
    __builtin_amdgcn_sched_barrier(0);
    if (kk == 0) {
#pragma unroll
      for (int mi = 0; mi < 4; ++mi)
#pragma unroll
        for (int ni = 0; ni < 2; ++ni) {
          acc0[mi][ni] = f32x4{0.f, 0.f, 0.f, 0.f};
          acc1[mi][ni] = f32x4{0.f, 0.f, 0.f, 0.f};
        }
    }
    {
      f16x8 bfr[2][2];
#pragma unroll
      for (int i = 0; i < 2; ++i) {
        const int rb = wn * 32 + i * 16 + nl;
        const int kb2 = (quad ^ ((rb >> 1) & 3)) * 8;
        bfr[0][i] = *(const f16x8*)&Bsw[be][0][rb][kb2];
        bfr[1][i] = *(const f16x8*)&Bsw[be][1][rb][kb2];
      }
      __builtin_amdgcn_s_setprio(1);
#pragma unroll
      for (int mi = 0; mi < 4; ++mi)
#pragma unroll
        for (int ni = 0; ni < 2; ++ni) {
          f32x4 c = acc0[mi][ni];
          c = __builtin_amdgcn_mfma_f32_16x16x32_f16(afc[0][mi], bfr[0][ni], c, 0, 0, 0);
          c = __builtin_amdgcn_mfma_f32_16x16x32_f16(afc[0][mi], bfr[1][ni], c, 0, 0, 0);
          c = __builtin_amdgcn_mfma_f32_16x16x32_f16(afc[1][mi], bfr[0][ni], c, 0, 0, 0);
          acc0[mi][ni] = c;
        }
      __builtin_amdgcn_s_setprio(0);
    }
    // ===== odd sub-step (t = (g/12)*2+1, reuses afc) =====
    if (g == 22)      asm volatile("s_waitcnt vmcnt(12)" ::: "memory");
    else if (g == 23) asm volatile("s_waitcnt vmcnt(8)"  ::: "memory");
    else              asm volatile("s_waitcnt vmcnt(14)" ::: "memory");
    __builtin_amdgcn_s_barrier();
    __builtin_amdgcn_sched_barrier(0);
    if (g < 23) LOAD_AF(afn, g + 1);         // af(g+1), ahead of B stages
    __builtin_amdgcn_sched_barrier(0);
    if (g < 22) STAGE_B(2 * g + 5);          // Bo(g+2)
    __builtin_amdgcn_sched_barrier(0);
    {
      f16x8 bfr[2][2];
#pragma unroll
      for (int i = 0; i < 2; ++i) {
        const int rb = wn * 32 + i * 16 + nl;
        const int kb2 = (quad ^ ((rb >> 1) & 3)) * 8;
        bfr[0][i] = *(const f16x8*)&Bsw[bo][0][rb][kb2];
        bfr[1][i] = *(const f16x8*)&Bsw[bo][1][rb][kb2];
      }
      __builtin_amdgcn_s_setprio(1);
#pragma unroll
      for (int mi = 0; mi < 4; ++mi)
#pragma unroll
        for (int ni = 0; ni < 2; ++ni) {
          f32x4 c = acc1[mi][ni];
          c = __builtin_amdgcn_mfma_f32_16x16x32_f16(afc[0][mi], bfr[0][ni], c, 0, 0, 0);
          c = __builtin_amdgcn_mfma_f32_16x16x32_f16(afc[0][mi], bfr[1][ni], c, 0, 0, 0);
          c = __builtin_amdgcn_mfma_f32_16x16x32_f16(afc[1][mi], bfr[0][ni], c, 0, 0, 0);
          acc1[mi][ni] = c;
        }
      __builtin_amdgcn_s_setprio(0);
    }
    if (kk == 11) {
      const int p2 = g / 12;
      epi(acc0, p2 * 2 + 0);
      epi(acc1, p2 * 2 + 1);
    }
  };

  // prologue FIFO order: Be(0)2, Bo(0)2, Be(1)2, af(0)8, Bo(1)2
  STAGE_B(0); STAGE_B(1); STAGE_B(2);
  LOAD_AF(afA, 0);
  STAGE_B(3);

#pragma unroll 1
  for (int gp = 0; gp < 12; ++gp) {
    sub(afA, afB, 2 * gp);
    sub(afB, afA, 2 * gp + 1);
  }
#undef STAGE_B
#undef LOAD_AF
}

// ---------------------------------------------------------------------------
// FUSED attention + LIF(0.5), v3 factorized (UNCHANGED from R9: validated).
// ---------------------------------------------------------------------------
#define USTR 232
#define GSTR 40
__global__ __launch_bounds__(256, 2) void attn_lif(
    const u32* __restrict__ qb, const u32* __restrict__ kb,
    const u32* __restrict__ vb, const float* __restrict__ policy,
    __bf16* __restrict__ sp) {
  __shared__ u32 qs[208], ks[224], vs_[224];
  __shared__ float ps[224];
  __shared__ __bf16 psp[3][224];
  __shared__ __bf16 Ul[3][32][USTR];   // U^T: [d][m]
  __shared__ __bf16 GT[3][32][GSTR];   // G^T: [d][c]
  const int bh = blockIdx.x;           // b*H + h
  const int bN = bh / Hn;
  const int h = bh - bN * Hn;
  const int tid = threadIdx.x;
  const int lane = tid & 63, wid = tid >> 6;
  const int quad = lane >> 4, nl = lane & 15;
  const int wm1 = wid >> 1, wn1 = wid & 1;
  const __bf16 one = (__bf16)1.0f, zero = (__bf16)0.0f;

  float vst[4][2][4] = {};

  for (int t = 0; t < Tn; ++t) {
    const int tb = t * Bn + bN;
    const int gid = tb * Hn + h;
    if (t) __syncthreads();
    for (int i = tid; i < 224; i += 256) {
      const bool in = i < Nn;
      if (i < 208) qs[i] = in ? qb[(size_t)gid * Nn + i] : 0u;
      ks[i] = in ? kb[(size_t)gid * Nn + i] : 0u;
      vs_[i] = in ? vb[(size_t)gid * Nn + i] : 0u;
      const float p = in ? policy[(size_t)tb * Nn + i] : 0.f;
      ps[i] = p;
      __bf16 hh, mm, ll;
      split3(p, hh, mm, ll);
      psp[0][i] = hh; psp[1][i] = mm; psp[2][i] = ll;
    }
    __syncthreads();

#pragma unroll
    for (int it = 0; it < 7; ++it) {
      const int idx = tid + it * 256;
      const int d = idx & 31, mg = idx >> 5;
      __bf16 u4[3][4];
#pragma unroll
      for (int j = 0; j < 4; ++j) {
        const int m = mg * 4 + j;
        const bool bit = (vs_[m] >> d) & 1u;
#pragma unroll
        for (int s = 0; s < 3; ++s)
          u4[s][j] = bit ? psp[s][m] : zero;
      }
#pragma unroll
      for (int s = 0; s < 3; ++s)
        *(bf16x4v*)&Ul[s][d][mg * 4] = *(bf16x4v*)u4[s];
    }
    __syncthreads();

    f32x4 gacc = {0.f, 0.f, 0.f, 0.f};
    const int crow = wm1 * 16 + nl;
    const int drow = wn1 * 16 + nl;
#pragma unroll
    for (int slab = 0; slab < 7; ++slab) {
      const int m0 = slab * 32 + quad * 8;
      u32 kw[8];
      *(uint4*)&kw[0] = *(const uint4*)&ks[m0];
      *(uint4*)&kw[4] = *(const uint4*)&ks[m0 + 4];
      __bf16 a8[8];
#pragma unroll
      for (int j = 0; j < 8; ++j)
        a8[j] = ((kw[j] >> crow) & 1u) ? one : zero;
      const bf16x8 af = *(const bf16x8*)a8;
#pragma unroll
      for (int s = 0; s < 3; ++s)
        gacc = __builtin_amdgcn_mfma_f32_16x16x32_bf16(
            af, *(const bf16x8*)&Ul[s][drow][slab * 32 + quad * 8], gacc, 0, 0, 0);
    }
#pragma unroll
    for (int r = 0; r < 4; ++r) {
      __bf16 gh, gm, gl;
      split3(gacc[r], gh, gm, gl);
      const int cc = wm1 * 16 + quad * 4 + r;
      GT[0][drow][cc] = gh;
      GT[1][drow][cc] = gm;
      GT[2][drow][cc] = gl;
    }
    __syncthreads();

    bf16x8 bfr2[3][2];
#pragma unroll
    for (int s = 0; s < 3; ++s)
#pragma unroll
      for (int nt = 0; nt < 2; ++nt)
        bfr2[s][nt] = *(const bf16x8*)&GT[s][nt * 16 + nl][quad * 8];

    f32x4 acc2[4][2] = {};
#pragma unroll
    for (int mi = 0; mi < 4; ++mi) {
      const int lt = wid + mi * 4;
      if (lt < 13) {
        const u32 qw = qs[lt * 16 + nl];
        __bf16 a8[8];
#pragma unroll
        for (int j = 0; j < 8; ++j)
          a8[j] = ((qw >> (quad * 8 + j)) & 1u) ? one : zero;
        const bf16x8 af2 = *(const bf16x8*)a8;
#pragma unroll
        for (int nt = 0; nt < 2; ++nt) {
          f32x4 c = acc2[mi][nt];
          c = __builtin_amdgcn_mfma_f32_16x16x32_bf16(af2, bfr2[0][nt], c, 0, 0, 0);
          c = __builtin_amdgcn_mfma_f32_16x16x32_bf16(af2, bfr2[1][nt], c, 0, 0, 0);
          c = __builtin_amdgcn_mfma_f32_16x16x32_bf16(af2, bfr2[2][nt], c, 0, 0, 0);
          acc2[mi][nt] = c;
        }
      }
    }
#pragma unroll
    for (int mi = 0; mi < 4; ++mi) {
      const int lt = wid + mi * 4;
      if (lt >= 13) continue;
#pragma unroll
      for (int r = 0; r < 4; ++r) {
        const int n = lt * 16 + quad * 4 + r;
        if (n >= Nn) continue;
        const float ann = (float)__popc(qs[n] & ks[n]);
        const float wd = ann * (1.0f - ps[n]);
        const u32 vn = vs_[n];
        __bf16* op = sp + (size_t)t * BCNn + ((size_t)bN * Nn + n) * Cn + h * 32;
#pragma unroll
        for (int nt = 0; nt < 2; ++nt) {
          const int d = nt * 16 + nl;
          const float bit = (float)((vn >> d) & 1u);
          const float y = (acc2[mi][nt][r] + wd * bit) * 0.25f;
          const float vv = vst[mi][nt][r];
          const float nv = vv + (y - vv) * 0.5f;
          const bool s = nv >= 0.5f;
          vst[mi][nt][r] = s ? 0.f : nv;
          op[d] = (__bf16)(s ? 1.0f : 0.0f);
        }
      }
    }
  }
}

// ---------------------------------------------------------------------------
// FUSED proj GEMM + LIF(1.0) -> out, v2 (UNCHANGED from R11: validated).
// ---------------------------------------------------------------------------
__global__ __launch_bounds__(256, 3) void gemm_proj_lif(
    const __bf16* __restrict__ sp, const __bf16* __restrict__ wspb,
    const float* __restrict__ shv, float* __restrict__ out)
{
  __shared__ __bf16 Bsw[5][64][32];      // B ring: slot g%5, 4KB each
  const int orig = blockIdx.x;
  const int xcd = orig & 7, i8 = orig >> 3;
  const int wgid = xcd * 73 + (xcd < 4 ? xcd : 4) + i8;
  const int colt = wgid / 6, ot = wgid - colt * 6;
  const int col0 = colt * 64;
  const int o0 = ot * 64;
  const int tid = threadIdx.x, lane = tid & 63, wid = tid >> 6;
  const int wm = wid >> 1, wn = wid & 1;
  const int quad = lane >> 4, nl = lane & 15;

  u32 afOff[3][2];
#pragma unroll
  for (int s = 0; s < 3; ++s)
#pragma unroll
    for (int mi = 0; mi < 2; ++mi)
      afOff[s][mi] = (u32)(((s * WSZ) + (ot * 4 + wm * 2 + mi) * 6144) * 2) +
                     (u32)(lane * 16);
  u32 bOff;
  {
    const int c = wid * 64 + lane;               // B chunk 0..255
    const int row = c >> 2, kb = c & 3;
    const int kbs = kb ^ ((row >> 1) & 3);
    bOff = (u32)(((size_t)(col0 + row) * Cn + kbs * 8) * 2);
  }
  const char* wB = (const char*)wspb;
  const char* sB = (const char*)sp;
  char* bD0 = (char*)&Bsw[0][0][0] + wid * 1024;

#define STAGE_B(g_) do {                                                   \
    const int t_ = ((g_) / 24) * 2 + ((g_) & 1);                           \
    const int kk_ = (((g_) % 24) >> 1);                                    \
    const u32 bk_ = (u32)(kk_ * 64) + (u32)t_ * (u32)(BCNn * 2);           \
    gl_lds16(sB + bOff + bk_, bD0 + ((g_) % 5) * 4096);                    \
  } while (0)
#define LOAD_AF(DST, g_) do {                                              \
    const u32 ak2_ = (u32)(((g_) % 12) * 1024);                            \
    _Pragma("unroll") for (int s_ = 0; s_ < 3; ++s_)                       \
    _Pragma("unroll") for (int m_ = 0; m_ < 2; ++m_)                       \
      DST[s_][m_] = *(const bf16x8*)(wB + afOff[s_][m_] + ak2_);           \
  } while (0)

  f32x4 sh_[2];
#pragma unroll
  for (int mi = 0; mi < 2; ++mi)
    sh_[mi] = *(const f32x4*)&shv[3 * Cn + o0 + wm * 32 + mi * 16 + quad * 4];

  f32x4 acc0[2][2], acc1[2][2];
  f32x4 vst[2][2] = {};   // LIF(1.0) membrane, persists across t
  bf16x8 afA[3][2], afB[3][2];

  auto epi = [&](f32x4 (&ac)[2][2], int t) {
#pragma unroll
    for (int mi = 0; mi < 2; ++mi) {
      const int ob = o0 + wm * 32 + mi * 16 + quad * 4;
#pragma unroll
      for (int ni = 0; ni < 2; ++ni) {
        const int col = col0 + wn * 32 + ni * 16 + nl;
        const int bb = col / Nn, nn = col - bb * Nn;
        float* op = out + (size_t)t * BCNn + (size_t)bb * CNn + nn;
#pragma unroll
        for (int r = 0; r < 4; ++r) {
          const float y = ac[mi][ni][r] + sh_[mi][r];
          const float vv = vst[mi][ni][r];
          const float nv = vv + (y - vv) * 0.5f;
          const bool sk = nv >= 1.0f;
          vst[mi][ni][r] = sk ? 0.f : nv;
          op[(size_t)(ob + r) * Nn] = sk ? 1.0f : 0.0f;
        }
      }
    }
  };

  auto sub = [&](bf16x8 (&afc)[3][2], bf16x8 (&afn)[3][2], int g) {
    const int kk = g % 12;
    const int be = (2 * g) % 5, bo = (2 * g + 1) % 5;
    // ===== even sub-step (t = (g/12)*2) =====
    if (g == 23) asm volatile("s_waitcnt vmcnt(0)" ::: "memory");
    else         asm volatile("s_waitcnt vmcnt(1)" ::: "memory");
    __builtin_amdgcn_s_barrier();
    __builtin_amdgcn_sched_barrier(0);
    if (g < 22) STAGE_B(2 * g + 4);          // Be(g+2)
    __builtin_amdgcn_sched_barrier(0);
    if (kk == 0) {
#pragma unroll
      for (int mi = 0; mi < 2; ++mi)
#pragma unroll
        for (int ni = 0; ni < 2; ++ni) {
          acc0[mi][ni] = f32x4{0.f, 0.f, 0.f, 0.f};
          acc1[mi][ni] = f32x4{0.f, 0.f, 0.f, 0.f};
        }
    }
    {
      bf16x8 bfr[2];
#pragma unroll
      for (int ni = 0; ni < 2; ++ni) {
        const int rb = wn * 32 + ni * 16 + nl;
        const int kb2 = (quad ^ ((rb >> 1) & 3)) * 8;
        bfr[ni] = *(const bf16x8*)&Bsw[be][rb][kb2];
      }
      __builtin_amdgcn_s_setprio(1);
#pragma unroll
      for (int mi = 0; mi < 2; ++mi)
#pragma unroll
        for (int ni = 0; ni < 2; ++ni) {
          f32x4 c = acc0[mi][ni];
          c = __builtin_amdgcn_mfma_f32_16x16x32_bf16(afc[0][mi], bfr[ni], c, 0, 0, 0);
          c = __builtin_amdgcn_mfma_f32_16x16x32_bf16(afc[1][mi], bfr[ni], c, 0, 0, 0);
          c = __builtin_amdgcn_mfma_f32_16x16x32_bf16(afc[2][mi], bfr[ni], c, 0, 0, 0);
          acc0[mi][ni] = c;
        }
      __builtin_amdgcn_s_setprio(0);
    }
    // ===== odd sub-step (t = (g/12)*2+1, reuses afc) =====
    if (g == 22)      asm volatile("s_waitcnt vmcnt(1)" ::: "memory");
    else if (g == 23) asm volatile("s_waitcnt vmcnt(0)" ::: "memory");
    else              asm volatile("s_waitcnt vmcnt(2)" ::: "memory");
    __builtin_amdgcn_s_barrier();
    __builtin_amdgcn_sched_barrier(0);
    if (g < 23) LOAD_AF(afn, g + 1);         // af(g+1)
    __builtin_amdgcn_sched_barrier(0);
    if (g < 22) STAGE_B(2 * g + 5);          // Bo(g+2)
    __builtin_amdgcn_sched_barrier(0);
    {
      bf16x8 bfr[2];
#pragma unroll
      for (int ni = 0; ni < 2; ++ni) {
        const int rb = wn * 32 + ni * 16 + nl;
        const int kb2 = (quad ^ ((rb >> 1) & 3)) * 8;
        bfr[ni] = *(const bf16x8*)&Bsw[bo][rb][kb2];
      }
      __builtin_amdgcn_s_setprio(1);
#pragma unroll
      for (int mi = 0; mi < 2; ++mi)
#pragma unroll
        for (int ni = 0; ni < 2; ++ni) {
          f32x4 c = acc1[mi][ni];
          c = __builtin_amdgcn_mfma_f32_16x16x32_bf16(afc[0][mi], bfr[ni], c, 0, 0, 0);
          c = __builtin_amdgcn_mfma_f32_16x16x32_bf16(afc[1][mi], bfr[ni], c, 0, 0, 0);
          c = __builtin_amdgcn_mfma_f32_16x16x32_bf16(afc[2][mi], bfr[ni], c, 0, 0, 0);
          acc1[mi][ni] = c;
        }
      __builtin_amdgcn_s_setprio(0);
    }
    if (kk == 11) {
      const int p2 = g / 12;
      epi(acc0, p2 * 2 + 0);
      epi(acc1, p2 * 2 + 1);
    }
  };

  // prologue FIFO: B0, B1, B2, af0(6), B3  -> slots 0,1,2,-,3 (distinct)
  STAGE_B(0); STAGE_B(1); STAGE_B(2);
  LOAD_AF(afA, 0);
  STAGE_B(3);

#pragma unroll 1
  for (int gp = 0; gp < 12; ++gp) {
    sub(afA, afB, 2 * gp);
    sub(afB, afA, 2 * gp + 1);
  }
#undef STAGE_B
#undef LOAD_AF
}

// ===========================================================================
extern "C" void kernel_launch(void* const* d_in, const int* in_sizes, int n_in,
                              void* d_out, int out_size, void* d_ws, size_t ws_size,
                              hipStream_t stream) {
  const float* x      = (const float*)d_in[0];
  const float* policy = (const float*)d_in[1];
  const float* qw = (const float*)d_in[2];
  const float* qg = (const float*)d_in[3];
  const float* qb_ = (const float*)d_in[4];
  const float* qm = (const float*)d_in[5];
  const float* qv = (const float*)d_in[6];
  const float* kw = (const float*)d_in[7];
  const float* kg = (const float*)d_in[8];
  const float* kbe = (const float*)d_in[9];
  const float* km = (const float*)d_in[10];
  const float* kv = (const float*)d_in[11];
  const float* vw = (const float*)d_in[12];
  const float* vg = (const float*)d_in[13];
  const float* vbe = (const float*)d_in[14];
  const float* vm = (const float*)d_in[15];
  const float* vv = (const float*)d_in[16];
  const float* pw = (const float*)d_in[17];
  const float* pg = (const float*)d_in[18];
  const float* pbe = (const float*)d_in[19];
  const float* pm = (const float*)d_in[20];
  const float* pv = (const float*)d_in[21];
  const float* pbias = (const float*)d_in[22];
  float* out = (float*)d_out;

  char* base = (char*)d_ws;
  _Float16* xs   = (_Float16*)base;                               // 38,535,168
  _Float16* wsp16 = (_Float16*)(base + (size_t)TBCNn * 4);        //  1,769,472
  __bf16* wspb   = (__bf16*)((char*)wsp16 + (size_t)6 * WSZ * 2); //    884,736
  float* shv     = (float*)((char*)wspb + (size_t)3 * WSZ * 2);   //      6,144
  u32* bq        = (u32*)((char*)shv + 4 * Cn * 4);               //  1,204,224 x3
  u32* bk = bq + PBITS;
  u32* bv = bk + PBITS;
  __bf16* sp     = (__bf16*)(bv + PBITS);                         // 19,267,584

  WSplitArgs wa;
  wa.w[0] = qw; wa.g[0] = qg; wa.be[0] = qb_; wa.mu[0] = qm; wa.va[0] = qv;
  wa.w[1] = kw; wa.g[1] = kg; wa.be[1] = kbe; wa.mu[1] = km; wa.va[1] = kv;
  wa.w[2] = vw; wa.g[2] = vg; wa.be[2] = vbe; wa.mu[2] = vm; wa.va[2] = vv;
  wa.w[3] = pw; wa.g[3] = pg; wa.be[3] = pbe; wa.mu[3] = pm; wa.va[3] = pv;
  wa.bias = pbias;
  prep<<<3840, 256, 0, stream>>>(wa, wsp16, wspb, shv, x, xs);

  gemm_qkv_lif<<<882, 256, 0, stream>>>(xs, wsp16, shv, bq, bk, bv);
  attn_lif<<<Bn * Hn, 256, 0, stream>>>(bq, bk, bv, policy, sp);
  gemm_proj_lif<<<588, 256, 0, stream>>>(sp, wspb, shv, out);
}

// Round 14
// 268.609 us; speedup vs baseline: 1.8202x; 1.0275x over previous
//
#include <hip/hip_runtime.h>

typedef unsigned int u32;
typedef __bf16 bf16x8 __attribute__((ext_vector_type(8)));
typedef __bf16 bf16x4v __attribute__((ext_vector_type(4)));
typedef _Float16 f16x8 __attribute__((ext_vector_type(8)));
typedef float f32x4 __attribute__((ext_vector_type(4)));

#define Tn 4
#define Bn 32
#define Cn 384
#define Nn 196
#define Hn 12
#define CNn (Cn*Nn)         // 75264
#define BCNn (Bn*CNn)       // 2408448
#define BHNn (Bn*Hn*Nn)     // 75264
#define PBITS (Tn*BHNn)     // 301056
#define TBCNn (Tn*BCNn)     // 9633792
#define NCOLS 6272          // B*N
#define WSZ 147456          // 384*384

// fp32 -> 3-way bf16 split (residual ~2^-24 rel)
__device__ __forceinline__ void split3(float v, __bf16& h, __bf16& m, __bf16& l) {
  h = (__bf16)v;  float r = v - (float)h;
  m = (__bf16)r;  float r2 = r - (float)m;
  l = (__bf16)r2;
}
// fp32 -> 2-way f16 split (residual ~2^-22 rel)
__device__ __forceinline__ void split2h(float v, _Float16& h, _Float16& l) {
  h = (_Float16)v;  l = (_Float16)(v - (float)h);
}

// direct global->LDS 16B copy: lane i lands at ldsbase + i*16 (wave-uniform base)
__device__ __forceinline__ void gl_lds16(const void* g, void* l) {
  __builtin_amdgcn_global_load_lds(
      (const __attribute__((address_space(1))) unsigned int*)g,
      (__attribute__((address_space(3))) unsigned int*)l, 16, 0, 0);
}

// ---------------------------------------------------------------------------
// MERGED prep. QKV weights (p<3) AND proj weights (p==3) emitted in
// FRAGMENT-TILED layout: (o,c) -> ((o>>4)*12+(c>>5))*512 + ((c>>3)&3)*128
// + (o&15)*8 + (c&7); an MFMA A-fragment is one coalesced dwordx4 at
// tilebase + lane*16 (no LDS staging in the GEMMs).
// ---------------------------------------------------------------------------
struct WSplitArgs {
  const float* w[4]; const float* g[4]; const float* be[4];
  const float* mu[4]; const float* va[4]; const float* bias;
};
__global__ __launch_bounds__(256) void prep(
    WSplitArgs a, _Float16* __restrict__ wsp16, __bf16* __restrict__ wspb,
    float* __restrict__ shv, const float* __restrict__ x,
    _Float16* __restrict__ xs) {
  __shared__ float tile[49 * 130];
  const int bx = blockIdx.x;
  const int tid = threadIdx.x;
  if (bx < 2304) {
    const int i = bx * 256 + tid;                 // < 589824
    const int p = i / WSZ, r = i - p * WSZ;
    const int o = r / Cn, cc = r - o * Cn;
    const float iv = a.g[p][o] / sqrtf(a.va[p][o] + 1e-5f);
    const float wv = a.w[p][r] * iv;
    const int toff = ((o >> 4) * 12 + (cc >> 5)) * 512 +
                     (((cc >> 3) & 3) << 7) + ((o & 15) << 3) + (cc & 7);
    if (p < 3) {
      _Float16 h, l;
      split2h(wv, h, l);
      wsp16[(size_t)(p * 2 + 0) * WSZ + toff] = h;
      wsp16[(size_t)(p * 2 + 1) * WSZ + toff] = l;
    } else {
      __bf16 h, m, l;
      split3(wv, h, m, l);
      wspb[(size_t)0 * WSZ + toff] = h;
      wspb[(size_t)1 * WSZ + toff] = m;
      wspb[(size_t)2 * WSZ + toff] = l;
    }
    if (cc == 0) {
      float sh = a.be[p][o] - a.mu[p][o] * iv;
      if (p == 3) sh += a.bias[o] * iv;
      shv[p * Cn + o] = sh;
    }
    return;
  }
  const int bid2 = bx - 2304;                     // < 1536
  const int t = bid2 & 3, b = (bid2 >> 2) & 31, zz = bid2 >> 7;
  const int ct = zz >> 2, nch = zz & 3;
  const int c0 = ct * 128, n0 = nch * 49;
  for (int idx = tid; idx < 49 * 128; idx += 256) {
    const int n = idx % 49, c = idx / 49;
    tile[n * 130 + c] = x[(size_t)t * BCNn + (size_t)b * CNn +
                          (size_t)(c0 + c) * Nn + n0 + n];
  }
  __syncthreads();
  for (int idx = tid; idx < 49 * 64; idx += 256) {
    const int cp = idx & 63, n = idx >> 6;
    const float v0 = tile[n * 130 + cp * 2];
    const float v1 = tile[n * 130 + cp * 2 + 1];
    _Float16 h0, l0, h1, l1;
    split2h(v0, h0, l0);
    split2h(v1, h1, l1);
    const size_t col = (size_t)t * NCOLS + (size_t)b * Nn + n0 + n;
    union { _Float16 f[2]; u32 u; } uh, ul;
    uh.f[0] = h0; uh.f[1] = h1;
    ul.f[0] = l0; ul.f[1] = l1;
    ((u32*)(xs + col * Cn + c0))[cp] = uh.u;
    ((u32*)(xs + (size_t)TBCNn + col * Cn + c0))[cp] = ul.u;
  }
}

// ---------------------------------------------------------------------------
// FUSED QKV GEMM + LIF(1.0) + bitpack, v6: SINGLE barrier per gg (24 vs 48).
// B-ring widened to 6 slots so both sub-steps' tiles (slots 2g,2g+1 mod 6)
// are disjoint from this gg's writes (2g+4,2g+5 mod 6, last read in gg-1 and
// protected by the gg barrier: gg-1's ds_reads complete before its MFMAs,
// which precede the barrier). FIFO per gg: Be2+af8+Bo2 -> barrier wait
// vmcnt(12) steady/g0/g22, vmcnt(8) g23. launch_bounds (256,2) UNTOUCHED
// (R12: a (256,3) hint made the allocator spill, +540MB scratch).
// ---------------------------------------------------------------------------
__global__ __launch_bounds__(256, 2) void gemm_qkv_lif(
    const _Float16* __restrict__ xs,    // [2][t][col][c] f16 pre-split
    const _Float16* __restrict__ wsp16, // [3][2] fragment-tiled iv-scaled f16
    const float* __restrict__ shv,      // [4][o]
    u32* __restrict__ bq, u32* __restrict__ bk, u32* __restrict__ bv)
{
  __shared__ _Float16 Bsw[6][2][64][32];    // B ring: slot tile%6, 8KB each
  const int orig = blockIdx.x;
  const int xcd = orig & 7, i8 = orig >> 3;
  const int wgid = xcd * 110 + (xcd < 2 ? xcd : 2) + i8;
  const int colt = wgid / 9, v = wgid - colt * 9;
  const int col0 = colt * 64;
  const int p = v / 3, mt = v - p * 3;
  const int o0 = mt * 128;
  const int tid = threadIdx.x, lane = tid & 63, wid = tid >> 6;
  const int wm = wid >> 1, wn = wid & 1;
  const int quad = lane >> 4, nl = lane & 15;
  u32* __restrict__ bits = (p == 0) ? bq : (p == 1) ? bk : bv;

  u32 afOff[2][4];
#pragma unroll
  for (int s = 0; s < 2; ++s)
#pragma unroll
    for (int mi = 0; mi < 4; ++mi)
      afOff[s][mi] = (u32)((((p * 2 + s) * WSZ) +
                            (mt * 8 + wm * 4 + mi) * 6144) * 2) +
                     (u32)(lane * 16);
  u32 bOff[2];
#pragma unroll
  for (int i = 0; i < 2; ++i) {
    const int c = i * 256 + wid * 64 + lane;     // B chunk 0..511
    const int s = c >> 8, rem = c & 255, row = rem >> 2, kb = rem & 3;
    const int kbs = kb ^ ((row >> 1) & 3);
    bOff[i] = (u32)(((size_t)s * TBCNn + (size_t)(col0 + row) * Cn + kbs * 8) * 2);
  }
  const char* wB = (const char*)wsp16;
  const char* xB = (const char*)xs;
  char* bD0 = (char*)&Bsw[0][0][0][0] + wid * 1024;

#define STAGE_B(g_) do {                                                   \
    const int t_ = ((g_) / 24) * 2 + ((g_) & 1);                           \
    const int kk_ = (((g_) % 24) >> 1);                                    \
    const u32 bk_ = (u32)(kk_ * 64) + (u32)t_ * (u32)(NCOLS * Cn * 2);     \
    char* d_ = bD0 + ((g_) % 6) * 8192;                                    \
    _Pragma("unroll") for (int i_ = 0; i_ < 2; ++i_)                       \
      gl_lds16(xB + bOff[i_] + bk_, d_ + i_ * 4096);                       \
  } while (0)
#define LOAD_AF(DST, g_) do {                                              \
    const u32 ak2_ = (u32)(((g_) % 12) * 1024);                            \
    _Pragma("unroll") for (int s_ = 0; s_ < 2; ++s_)                       \
    _Pragma("unroll") for (int m_ = 0; m_ < 4; ++m_)                       \
      DST[s_][m_] = *(const f16x8*)(wB + afOff[s_][m_] + ak2_);            \
  } while (0)

  f32x4 sh_[4];
#pragma unroll
  for (int mi = 0; mi < 4; ++mi)
    sh_[mi] = *(const f32x4*)&shv[p * Cn + o0 + wm * 64 + mi * 16 + quad * 4];

  f32x4 acc0[4][2], acc1[4][2];
  f32x4 vst[4][2] = {};
  f16x8 afA[2][4], afB[2][4];

  auto epi = [&](f32x4 (&ac)[4][2], int t) {
#pragma unroll
    for (int ni = 0; ni < 2; ++ni) {
      u32 w0 = 0, w1 = 0;
#pragma unroll
      for (int mi = 0; mi < 4; ++mi) {
#pragma unroll
        for (int r = 0; r < 4; ++r) {
          const float y = ac[mi][ni][r] + sh_[mi][r];
          const float vv = vst[mi][ni][r];
          const float nv = vv + (y - vv) * 0.5f;
          const bool sk = nv >= 1.0f;
          vst[mi][ni][r] = sk ? 0.f : nv;
          const u32 b1 = sk ? 1u : 0u;
          const int pos = ((mi & 1) << 4) + (quad << 2) + r;
          if (mi < 2) w0 |= b1 << pos; else w1 |= b1 << pos;
        }
      }
      w0 |= __shfl_xor(w0, 16); w0 |= __shfl_xor(w0, 32);
      w1 |= __shfl_xor(w1, 16); w1 |= __shfl_xor(w1, 32);
      if (quad == 0) {
        const int col = col0 + wn * 32 + ni * 16 + nl;
        const int bb = col / Nn, nn = col - bb * Nn;
        u32* bp = bits + (size_t)t * BHNn +
                  ((size_t)bb * Hn + (mt * 4 + wm * 2)) * Nn + nn;
        bp[0] = w0;
        bp[Nn] = w1;
      }
    }
  };

  auto sub = [&](f16x8 (&afc)[2][4], f16x8 (&afn)[2][4], int g) {
    const int kk = g % 12;
    const int be = (2 * g) % 6, bo = (2 * g + 1) % 6;
    // single barrier per gg: wait for Be(g)+Bo(g) landed (FIFO trace)
    if (g == 23) asm volatile("s_waitcnt vmcnt(8)"  ::: "memory");
    else         asm volatile("s_waitcnt vmcnt(12)" ::: "memory");
    __builtin_amdgcn_s_barrier();
    __builtin_amdgcn_sched_barrier(0);
    if (g < 22) STAGE_B(2 * g + 4);          // Be(g+2)
    if (g < 23) LOAD_AF(afn, g + 1);         // af(g+1)
    if (g < 22) STAGE_B(2 * g + 5);          // Bo(g+2)
    __builtin_amdgcn_sched_barrier(0);
    if (kk == 0) {
#pragma unroll
      for (int mi = 0; mi < 4; ++mi)
#pragma unroll
        for (int ni = 0; ni < 2; ++ni) {
          acc0[mi][ni] = f32x4{0.f, 0.f, 0.f, 0.f};
          acc1[mi][ni] = f32x4{0.f, 0.f, 0.f, 0.f};
        }
    }
    {
      f16x8 bfrE[2][2], bfrO[2][2];
#pragma unroll
      for (int i = 0; i < 2; ++i) {
        const int rb = wn * 32 + i * 16 + nl;
        const int kb2 = (quad ^ ((rb >> 1) & 3)) * 8;
        bfrE[0][i] = *(const f16x8*)&Bsw[be][0][rb][kb2];
        bfrE[1][i] = *(const f16x8*)&Bsw[be][1][rb][kb2];
        bfrO[0][i] = *(const f16x8*)&Bsw[bo][0][rb][kb2];
        bfrO[1][i] = *(const f16x8*)&Bsw[bo][1][rb][kb2];
      }
      __builtin_amdgcn_s_setprio(1);
#pragma unroll
      for (int mi = 0; mi < 4; ++mi)
#pragma unroll
        for (int ni = 0; ni < 2; ++ni) {
          f32x4 c = acc0[mi][ni];
          c = __builtin_amdgcn_mfma_f32_16x16x32_f16(afc[0][mi], bfrE[0][ni], c, 0, 0, 0);
          c = __builtin_amdgcn_mfma_f32_16x16x32_f16(afc[0][mi], bfrE[1][ni], c, 0, 0, 0);
          c = __builtin_amdgcn_mfma_f32_16x16x32_f16(afc[1][mi], bfrE[0][ni], c, 0, 0, 0);
          acc0[mi][ni] = c;
          f32x4 d = acc1[mi][ni];
          d = __builtin_amdgcn_mfma_f32_16x16x32_f16(afc[0][mi], bfrO[0][ni], d, 0, 0, 0);
          d = __builtin_amdgcn_mfma_f32_16x16x32_f16(afc[0][mi], bfrO[1][ni], d, 0, 0, 0);
          d = __builtin_amdgcn_mfma_f32_16x16x32_f16(afc[1][mi], bfrO[0][ni], d, 0, 0, 0);
          acc1[mi][ni] = d;
        }
      __builtin_amdgcn_s_setprio(0);
    }
    if (kk == 11) {
      const int p2 = g / 12;
      epi(acc0, p2 * 2 + 0);
      epi(acc1, p2 * 2 + 1);
    }
  };

  // prologue FIFO order: B0(2), B1(2), B2(2), af(0)8, B3(2) -> slots 0,1,2,3
  STAGE_B(0); STAGE_B(1); STAGE_B(2);
  LOAD_AF(afA, 0);
  STAGE_B(3);

#pragma unroll 1
  for (int gp = 0; gp < 12; ++gp) {
    sub(afA, afB, 2 * gp);
    sub(afB, afA, 2 * gp + 1);
  }
#undef STAGE_B
#undef LOAD_AF
}

// ---------------------------------------------------------------------------
// FUSED attention + LIF(0.5), v3 factorized (UNCHANGED from R9: validated).
// ---------------------------------------------------------------------------
#define USTR 232
#define GSTR 40
__global__ __launch_bounds__(256, 2) void attn_lif(
    const u32* __restrict__ qb, const u32* __restrict__ kb,
    const u32* __restrict__ vb, const float* __restrict__ policy,
    __bf16* __restrict__ sp) {
  __shared__ u32 qs[208], ks[224], vs_[224];
  __shared__ float ps[224];
  __shared__ __bf16 psp[3][224];
  __shared__ __bf16 Ul[3][32][USTR];   // U^T: [d][m]
  __shared__ __bf16 GT[3][32][GSTR];   // G^T: [d][c]
  const int bh = blockIdx.x;           // b*H + h
  const int bN = bh / Hn;
  const int h = bh - bN * Hn;
  const int tid = threadIdx.x;
  const int lane = tid & 63, wid = tid >> 6;
  const int quad = lane >> 4, nl = lane & 15;
  const int wm1 = wid >> 1, wn1 = wid & 1;
  const __bf16 one = (__bf16)1.0f, zero = (__bf16)0.0f;

  float vst[4][2][4] = {};

  for (int t = 0; t < Tn; ++t) {
    const int tb = t * Bn + bN;
    const int gid = tb * Hn + h;
    if (t) __syncthreads();
    for (int i = tid; i < 224; i += 256) {
      const bool in = i < Nn;
      if (i < 208) qs[i] = in ? qb[(size_t)gid * Nn + i] : 0u;
      ks[i] = in ? kb[(size_t)gid * Nn + i] : 0u;
      vs_[i] = in ? vb[(size_t)gid * Nn + i] : 0u;
      const float p = in ? policy[(size_t)tb * Nn + i] : 0.f;
      ps[i] = p;
      __bf16 hh, mm, ll;
      split3(p, hh, mm, ll);
      psp[0][i] = hh; psp[1][i] = mm; psp[2][i] = ll;
    }
    __syncthreads();

#pragma unroll
    for (int it = 0; it < 7; ++it) {
      const int idx = tid + it * 256;
      const int d = idx & 31, mg = idx >> 5;
      __bf16 u4[3][4];
#pragma unroll
      for (int j = 0; j < 4; ++j) {
        const int m = mg * 4 + j;
        const bool bit = (vs_[m] >> d) & 1u;
#pragma unroll
        for (int s = 0; s < 3; ++s)
          u4[s][j] = bit ? psp[s][m] : zero;
      }
#pragma unroll
      for (int s = 0; s < 3; ++s)
        *(bf16x4v*)&Ul[s][d][mg * 4] = *(bf16x4v*)u4[s];
    }
    __syncthreads();

    f32x4 gacc = {0.f, 0.f, 0.f, 0.f};
    const int crow = wm1 * 16 + nl;
    const int drow = wn1 * 16 + nl;
#pragma unroll
    for (int slab = 0; slab < 7; ++slab) {
      const int m0 = slab * 32 + quad * 8;
      u32 kw[8];
      *(uint4*)&kw[0] = *(const uint4*)&ks[m0];
      *(uint4*)&kw[4] = *(const uint4*)&ks[m0 + 4];
      __bf16 a8[8];
#pragma unroll
      for (int j = 0; j < 8; ++j)
        a8[j] = ((kw[j] >> crow) & 1u) ? one : zero;
      const bf16x8 af = *(const bf16x8*)a8;
#pragma unroll
      for (int s = 0; s < 3; ++s)
        gacc = __builtin_amdgcn_mfma_f32_16x16x32_bf16(
            af, *(const bf16x8*)&Ul[s][drow][slab * 32 + quad * 8], gacc, 0, 0, 0);
    }
#pragma unroll
    for (int r = 0; r < 4; ++r) {
      __bf16 gh, gm, gl;
      split3(gacc[r], gh, gm, gl);
      const int cc = wm1 * 16 + quad * 4 + r;
      GT[0][drow][cc] = gh;
      GT[1][drow][cc] = gm;
      GT[2][drow][cc] = gl;
    }
    __syncthreads();

    bf16x8 bfr2[3][2];
#pragma unroll
    for (int s = 0; s < 3; ++s)
#pragma unroll
      for (int nt = 0; nt < 2; ++nt)
        bfr2[s][nt] = *(const bf16x8*)&GT[s][nt * 16 + nl][quad * 8];

    f32x4 acc2[4][2] = {};
#pragma unroll
    for (int mi = 0; mi < 4; ++mi) {
      const int lt = wid + mi * 4;
      if (lt < 13) {
        const u32 qw = qs[lt * 16 + nl];
        __bf16 a8[8];
#pragma unroll
        for (int j = 0; j < 8; ++j)
          a8[j] = ((qw >> (quad * 8 + j)) & 1u) ? one : zero;
        const bf16x8 af2 = *(const bf16x8*)a8;
#pragma unroll
        for (int nt = 0; nt < 2; ++nt) {
          f32x4 c = acc2[mi][nt];
          c = __builtin_amdgcn_mfma_f32_16x16x32_bf16(af2, bfr2[0][nt], c, 0, 0, 0);
          c = __builtin_amdgcn_mfma_f32_16x16x32_bf16(af2, bfr2[1][nt], c, 0, 0, 0);
          c = __builtin_amdgcn_mfma_f32_16x16x32_bf16(af2, bfr2[2][nt], c, 0, 0, 0);
          acc2[mi][nt] = c;
        }
      }
    }
#pragma unroll
    for (int mi = 0; mi < 4; ++mi) {
      const int lt = wid + mi * 4;
      if (lt >= 13) continue;
#pragma unroll
      for (int r = 0; r < 4; ++r) {
        const int n = lt * 16 + quad * 4 + r;
        if (n >= Nn) continue;
        const float ann = (float)__popc(qs[n] & ks[n]);
        const float wd = ann * (1.0f - ps[n]);
        const u32 vn = vs_[n];
        __bf16* op = sp + (size_t)t * BCNn + ((size_t)bN * Nn + n) * Cn + h * 32;
#pragma unroll
        for (int nt = 0; nt < 2; ++nt) {
          const int d = nt * 16 + nl;
          const float bit = (float)((vn >> d) & 1u);
          const float y = (acc2[mi][nt][r] + wd * bit) * 0.25f;
          const float vv = vst[mi][nt][r];
          const float nv = vv + (y - vv) * 0.5f;
          const bool s = nv >= 0.5f;
          vst[mi][nt][r] = s ? 0.f : nv;
          op[d] = (__bf16)(s ? 1.0f : 0.0f);
        }
      }
    }
  }
}

// ---------------------------------------------------------------------------
// FUSED proj GEMM + LIF(1.0) -> out, v3: single barrier per gg (ring 6).
// FIFO per gg: Be1+af6+Bo1 -> barrier wait vmcnt(8) steady/g0/g22, vmcnt(6)
// g23. Same slot-disjointness proof as gemm_qkv v6.
// ---------------------------------------------------------------------------
__global__ __launch_bounds__(256, 3) void gemm_proj_lif(
    const __bf16* __restrict__ sp, const __bf16* __restrict__ wspb,
    const float* __restrict__ shv, float* __restrict__ out)
{
  __shared__ __bf16 Bsw[6][64][32];      // B ring: slot tile%6, 4KB each
  const int orig = blockIdx.x;
  const int xcd = orig & 7, i8 = orig >> 3;
  const int wgid = xcd * 73 + (xcd < 4 ? xcd : 4) + i8;
  const int colt = wgid / 6, ot = wgid - colt * 6;
  const int col0 = colt * 64;
  const int o0 = ot * 64;
  const int tid = threadIdx.x, lane = tid & 63, wid = tid >> 6;
  const int wm = wid >> 1, wn = wid & 1;
  const int quad = lane >> 4, nl = lane & 15;

  u32 afOff[3][2];
#pragma unroll
  for (int s = 0; s < 3; ++s)
#pragma unroll
    for (int mi = 0; mi < 2; ++mi)
      afOff[s][mi] = (u32)(((s * WSZ) + (ot * 4 + wm * 2 + mi) * 6144) * 2) +
                     (u32)(lane * 16);
  u32 bOff;
  {
    const int c = wid * 64 + lane;               // B chunk 0..255
    const int row = c >> 2, kb = c & 3;
    const int kbs = kb ^ ((row >> 1) & 3);
    bOff = (u32)(((size_t)(col0 + row) * Cn + kbs * 8) * 2);
  }
  const char* wB = (const char*)wspb;
  const char* sB = (const char*)sp;
  char* bD0 = (char*)&Bsw[0][0][0] + wid * 1024;

#define STAGE_B(g_) do {                                                   \
    const int t_ = ((g_) / 24) * 2 + ((g_) & 1);                           \
    const int kk_ = (((g_) % 24) >> 1);                                    \
    const u32 bk_ = (u32)(kk_ * 64) + (u32)t_ * (u32)(BCNn * 2);           \
    gl_lds16(sB + bOff + bk_, bD0 + ((g_) % 6) * 4096);                    \
  } while (0)
#define LOAD_AF(DST, g_) do {                                              \
    const u32 ak2_ = (u32)(((g_) % 12) * 1024);                            \
    _Pragma("unroll") for (int s_ = 0; s_ < 3; ++s_)                       \
    _Pragma("unroll") for (int m_ = 0; m_ < 2; ++m_)                       \
      DST[s_][m_] = *(const bf16x8*)(wB + afOff[s_][m_] + ak2_);           \
  } while (0)

  f32x4 sh_[2];
#pragma unroll
  for (int mi = 0; mi < 2; ++mi)
    sh_[mi] = *(const f32x4*)&shv[3 * Cn + o0 + wm * 32 + mi * 16 + quad * 4];

  f32x4 acc0[2][2], acc1[2][2];
  f32x4 vst[2][2] = {};   // LIF(1.0) membrane, persists across t
  bf16x8 afA[3][2], afB[3][2];

  auto epi = [&](f32x4 (&ac)[2][2], int t) {
#pragma unroll
    for (int mi = 0; mi < 2; ++mi) {
      const int ob = o0 + wm * 32 + mi * 16 + quad * 4;
#pragma unroll
      for (int ni = 0; ni < 2; ++ni) {
        const int col = col0 + wn * 32 + ni * 16 + nl;
        const int bb = col / Nn, nn = col - bb * Nn;
        float* op = out + (size_t)t * BCNn + (size_t)bb * CNn + nn;
#pragma unroll
        for (int r = 0; r < 4; ++r) {
          const float y = ac[mi][ni][r] + sh_[mi][r];
          const float vv = vst[mi][ni][r];
          const float nv = vv + (y - vv) * 0.5f;
          const bool sk = nv >= 1.0f;
          vst[mi][ni][r] = sk ? 0.f : nv;
          op[(size_t)(ob + r) * Nn] = sk ? 1.0f : 0.0f;
        }
      }
    }
  };

  auto sub = [&](bf16x8 (&afc)[3][2], bf16x8 (&afn)[3][2], int g) {
    const int kk = g % 12;
    const int be = (2 * g) % 6, bo = (2 * g + 1) % 6;
    if (g == 23) asm volatile("s_waitcnt vmcnt(6)" ::: "memory");
    else         asm volatile("s_waitcnt vmcnt(8)" ::: "memory");
    __builtin_amdgcn_s_barrier();
    __builtin_amdgcn_sched_barrier(0);
    if (g < 22) STAGE_B(2 * g + 4);          // Be(g+2)
    if (g < 23) LOAD_AF(afn, g + 1);         // af(g+1)
    if (g < 22) STAGE_B(2 * g + 5);          // Bo(g+2)
    __builtin_amdgcn_sched_barrier(0);
    if (kk == 0) {
#pragma unroll
      for (int mi = 0; mi < 2; ++mi)
#pragma unroll
        for (int ni = 0; ni < 2; ++ni) {
          acc0[mi][ni] = f32x4{0.f, 0.f, 0.f, 0.f};
          acc1[mi][ni] = f32x4{0.f, 0.f, 0.f, 0.f};
        }
    }
    {
      bf16x8 bfrE[2], bfrO[2];
#pragma unroll
      for (int ni = 0; ni < 2; ++ni) {
        const int rb = wn * 32 + ni * 16 + nl;
        const int kb2 = (quad ^ ((rb >> 1) & 3)) * 8;
        bfrE[ni] = *(const bf16x8*)&Bsw[be][rb][kb2];
        bfrO[ni] = *(const bf16x8*)&Bsw[bo][rb][kb2];
      }
      __builtin_amdgcn_s_setprio(1);
#pragma unroll
      for (int mi = 0; mi < 2; ++mi)
#pragma unroll
        for (int ni = 0; ni < 2; ++ni) {
          f32x4 c = acc0[mi][ni];
          c = __builtin_amdgcn_mfma_f32_16x16x32_bf16(afc[0][mi], bfrE[ni], c, 0, 0, 0);
          c = __builtin_amdgcn_mfma_f32_16x16x32_bf16(afc[1][mi], bfrE[ni], c, 0, 0, 0);
          c = __builtin_amdgcn_mfma_f32_16x16x32_bf16(afc[2][mi], bfrE[ni], c, 0, 0, 0);
          acc0[mi][ni] = c;
          f32x4 d = acc1[mi][ni];
          d = __builtin_amdgcn_mfma_f32_16x16x32_bf16(afc[0][mi], bfrO[ni], d, 0, 0, 0);
          d = __builtin_amdgcn_mfma_f32_16x16x32_bf16(afc[1][mi], bfrO[ni], d, 0, 0, 0);
          d = __builtin_amdgcn_mfma_f32_16x16x32_bf16(afc[2][mi], bfrO[ni], d, 0, 0, 0);
          acc1[mi][ni] = d;
        }
      __builtin_amdgcn_s_setprio(0);
    }
    if (kk == 11) {
      const int p2 = g / 12;
      epi(acc0, p2 * 2 + 0);
      epi(acc1, p2 * 2 + 1);
    }
  };

  // prologue FIFO: B0, B1, B2, af0(6), B3 -> slots 0,1,2,3 (distinct)
  STAGE_B(0); STAGE_B(1); STAGE_B(2);
  LOAD_AF(afA, 0);
  STAGE_B(3);

#pragma unroll 1
  for (int gp = 0; gp < 12; ++gp) {
    sub(afA, afB, 2 * gp);
    sub(afB, afA, 2 * gp + 1);
  }
#undef STAGE_B
#undef LOAD_AF
}

// ===========================================================================
extern "C" void kernel_launch(void* const* d_in, const int* in_sizes, int n_in,
                              void* d_out, int out_size, void* d_ws, size_t ws_size,
                              hipStream_t stream) {
  const float* x      = (const float*)d_in[0];
  const float* policy = (const float*)d_in[1];
  const float* qw = (const float*)d_in[2];
  const float* qg = (const float*)d_in[3];
  const float* qb_ = (const float*)d_in[4];
  const float* qm = (const float*)d_in[5];
  const float* qv = (const float*)d_in[6];
  const float* kw = (const float*)d_in[7];
  const float* kg = (const float*)d_in[8];
  const float* kbe = (const float*)d_in[9];
  const float* km = (const float*)d_in[10];
  const float* kv = (const float*)d_in[11];
  const float* vw = (const float*)d_in[12];
  const float* vg = (const float*)d_in[13];
  const float* vbe = (const float*)d_in[14];
  const float* vm = (const float*)d_in[15];
  const float* vv = (const float*)d_in[16];
  const float* pw = (const float*)d_in[17];
  const float* pg = (const float*)d_in[18];
  const float* pbe = (const float*)d_in[19];
  const float* pm = (const float*)d_in[20];
  const float* pv = (const float*)d_in[21];
  const float* pbias = (const float*)d_in[22];
  float* out = (float*)d_out;

  char* base = (char*)d_ws;
  _Float16* xs   = (_Float16*)base;                               // 38,535,168
  _Float16* wsp16 = (_Float16*)(base + (size_t)TBCNn * 4);        //  1,769,472
  __bf16* wspb   = (__bf16*)((char*)wsp16 + (size_t)6 * WSZ * 2); //    884,736
  float* shv     = (float*)((char*)wspb + (size_t)3 * WSZ * 2);   //      6,144
  u32* bq        = (u32*)((char*)shv + 4 * Cn * 4);               //  1,204,224 x3
  u32* bk = bq + PBITS;
  u32* bv = bk + PBITS;
  __bf16* sp     = (__bf16*)(bv + PBITS);                         // 19,267,584

  WSplitArgs wa;
  wa.w[0] = qw; wa.g[0] = qg; wa.be[0] = qb_; wa.mu[0] = qm; wa.va[0] = qv;
  wa.w[1] = kw; wa.g[1] = kg; wa.be[1] = kbe; wa.mu[1] = km; wa.va[1] = kv;
  wa.w[2] = vw; wa.g[2] = vg; wa.be[2] = vbe; wa.mu[2] = vm; wa.va[2] = vv;
  wa.w[3] = pw; wa.g[3] = pg; wa.be[3] = pbe; wa.mu[3] = pm; wa.va[3] = pv;
  wa.bias = pbias;
  prep<<<3840, 256, 0, stream>>>(wa, wsp16, wspb, shv, x, xs);

  gemm_qkv_lif<<<882, 256, 0, stream>>>(xs, wsp16, shv, bq, bk, bv);
  attn_lif<<<Bn * Hn, 256, 0, stream>>>(bq, bk, bv, policy, sp);
  gemm_proj_lif<<<588, 256, 0, stream>>>(sp, wspb, shv, out);
}